// Round 10
// baseline (194.276 us; speedup 1.0000x reference)
//
#include <hip/hip_runtime.h>

// LogicGateNetwork, fully fused, 4 batch rows per block.
// Single 128 KB LDS buffer of 16384 half4 entries (feature -> 4 batch rows).
// No ping-pong: each layer reads into registers, barriers, writes IN PLACE.
// One ds_read_b64 serves 4 batch rows -> LDS pipe work (measured bottleneck)
// halves vs the half2 version; table traffic from L2 halves too.

#define NBATCH 2048
#define IN_DIM 8192
#define HID 16384
#define OUT_DIM 1000
#define NTOT (4 * HID + OUT_DIM)   // 66536 neurons total

typedef __attribute__((ext_vector_type(4))) _Float16 half4;

// GATE_COEF (16 gates x 4 coefficients), row-major.
__device__ __constant__ float GC_dev[64] = {
    0, 0, 0, 0,   0, 0, 0, 1,   0, 1, 0, -1,  0, 1, 0, 0,
    0, 0, 1, -1,  0, 0, 1, 0,   0, 1, 1, -2,  0, 1, 1, -1,
    1, -1, -1, 1, 1, -1, -1, 2, 1, 0, -1, 0,  1, 0, -1, 1,
    1, -1, 0, 0,  1, -1, 0, 1,  1, 0, 0, -1,  1, 0, 0, 0
};

struct PrepArgs {
    const float* w[5];
    const int* ia[5];
    const int* ib[5];
};

// One thread per neuron: coef = softmax(w_row) @ GATE_COEF -> half4,
// idx = ia | (ib<<16).
__global__ __launch_bounds__(256) void prep_kernel(
    PrepArgs args, half4* __restrict__ coefT, unsigned int* __restrict__ idxT) {
    int g = blockIdx.x * 256 + threadIdx.x;
    if (g >= NTOT) return;
    int l = (g < 4 * HID) ? (g >> 14) : 4;
    int j = g - l * HID;

    const float* wrow = args.w[l] + (size_t)j * 16;
    float v[16];
    const float4* w4 = (const float4*)wrow;
#pragma unroll
    for (int i = 0; i < 4; ++i) {
        float4 t = w4[i];
        v[4 * i + 0] = t.x; v[4 * i + 1] = t.y; v[4 * i + 2] = t.z; v[4 * i + 3] = t.w;
    }
    float m = v[0];
#pragma unroll
    for (int g2 = 1; g2 < 16; ++g2) m = fmaxf(m, v[g2]);
    float s = 0.f;
#pragma unroll
    for (int g2 = 0; g2 < 16; ++g2) { v[g2] = __expf(v[g2] - m); s += v[g2]; }
    float inv = 1.f / s;
    float c0 = 0.f, c1 = 0.f, c2 = 0.f, c3 = 0.f;
#pragma unroll
    for (int g2 = 0; g2 < 16; ++g2) {
        c0 += v[g2] * GC_dev[g2 * 4 + 0];
        c1 += v[g2] * GC_dev[g2 * 4 + 1];
        c2 += v[g2] * GC_dev[g2 * 4 + 2];
        c3 += v[g2] * GC_dev[g2 * 4 + 3];
    }
    half4 c;
    c[0] = (_Float16)(c0 * inv); c[1] = (_Float16)(c1 * inv);
    c[2] = (_Float16)(c2 * inv); c[3] = (_Float16)(c3 * inv);
    coefT[g] = c;
    idxT[g] = (unsigned int)args.ia[l][j] | ((unsigned int)args.ib[l][j] << 16);
}

// Block bp owns batch rows 4*bp .. 4*bp+3. Dynamic LDS: half4 lds[HID]
// (128 KB); entry f holds feature f's activation for all 4 rows.
// Layers update the buffer in place (reads -> regs -> barrier -> writes).
__global__ __launch_bounds__(1024) void fused_kernel(
    const float* __restrict__ x, const half4* __restrict__ coefT,
    const unsigned int* __restrict__ idxT, float* __restrict__ out) {
    extern __shared__ half4 lds[];   // HID entries = 131072 B
    int bp = blockIdx.x;
    int t = threadIdx.x;  // 0..1023
    int r0 = 4 * bp;

    // Stage x rows r0..r0+3: thread t handles feature f = t + 1024*i.
    // Global: 4B/lane coalesced; LDS: b64 stride-8B -> conflict-free.
    const float* x0 = x + (size_t)r0 * IN_DIM;
#pragma unroll
    for (int i = 0; i < 8; ++i) {
        int f = i * 1024 + t;
        half4 h;
        h[0] = (_Float16)x0[f];
        h[1] = (_Float16)x0[IN_DIM + f];
        h[2] = (_Float16)x0[2 * IN_DIM + f];
        h[3] = (_Float16)x0[3 * IN_DIM + f];
        lds[f] = h;
    }
    __syncthreads();

    int tab = 0;
    for (int l = 0; l < 4; ++l) {
        half4 res[16];
#pragma unroll
        for (int k = 0; k < 16; ++k) {
            int j = k * 1024 + t;
            unsigned int idx = idxT[tab + j];
            half4 c = coefT[tab + j];
            half4 pa = lds[idx & 0xFFFFu];
            half4 pb = lds[idx >> 16];
            float c0 = (float)c[0], c1 = (float)c[1];
            float c2 = (float)c[2], c3 = (float)c[3];
            half4 r;
#pragma unroll
            for (int i = 0; i < 4; ++i) {
                float a = (float)pa[i];
                float b = (float)pb[i];
                // c0 + c1 a + c2 b + c3 ab = (c3 b + c1) a + (c2 b + c0)
                r[i] = (_Float16)fmaf(fmaf(c3, b, c1), a, fmaf(c2, b, c0));
            }
            res[k] = r;
        }
        __syncthreads();   // all reads of this layer done
#pragma unroll
        for (int k = 0; k < 16; ++k) lds[k * 1024 + t] = res[k];
        tab += HID;
        __syncthreads();   // all writes visible for next layer
    }

    // Final layer (1000 neurons) -> global fp32, coalesced per row.
    if (t < OUT_DIM) {
        unsigned int idx = idxT[tab + t];
        half4 c = coefT[tab + t];
        half4 pa = lds[idx & 0xFFFFu];
        half4 pb = lds[idx >> 16];
        float c0 = (float)c[0], c1 = (float)c[1];
        float c2 = (float)c[2], c3 = (float)c[3];
#pragma unroll
        for (int i = 0; i < 4; ++i) {
            float a = (float)pa[i];
            float b = (float)pb[i];
            out[(size_t)(r0 + i) * OUT_DIM + t] =
                fmaf(fmaf(c3, b, c1), a, fmaf(c2, b, c0));
        }
    }
}

extern "C" void kernel_launch(void* const* d_in, const int* in_sizes, int n_in,
                              void* d_out, int out_size, void* d_ws, size_t ws_size,
                              hipStream_t stream) {
    // Input dict order: x, then (w_i, ia_i, ib_i) for i=0..4.
    const float* x = (const float*)d_in[0];
    PrepArgs args;
    for (int i = 0; i < 5; ++i) {
        args.w[i]  = (const float*)d_in[1 + 3 * i];
        args.ia[i] = (const int*)d_in[2 + 3 * i];
        args.ib[i] = (const int*)d_in[3 + 3 * i];
    }

    // Workspace: packed neuron tables (~0.8 MB; rebuilt every call).
    char* ws = (char*)d_ws;
    half4* coefT = (half4*)ws;                                   // NTOT * 8B
    size_t coefBytes = ((size_t)NTOT * 8 + 255) & ~(size_t)255;
    unsigned int* idxT = (unsigned int*)(ws + coefBytes);        // NTOT * 4B

    prep_kernel<<<(NTOT + 255) / 256, 256, 0, stream>>>(args, coefT, idxT);
    fused_kernel<<<NBATCH / 4, 1024, HID * sizeof(half4), stream>>>(
        x, coefT, idxT, (float*)d_out);
}